// Round 3
// baseline (759.990 us; speedup 1.0000x reference)
//
#include <hip/hip_runtime.h>
#include <math.h>

#define BATCH 128
#define TLEN 512
#define XF 266
#define NF 96
#define HID 192
#define NC 250

// ---------------- fast activations (v_exp_f32 / v_rcp_f32) ----------------

__device__ __forceinline__ float fast_sigmoid(float x) {
  float t = __expf(-x);                       // v_exp_f32 path
  return __builtin_amdgcn_rcpf(1.f + t);      // 1/(1+e^-x)
}

__device__ __forceinline__ float fast_tanh(float x) {
  float ax = fabsf(x);
  float t = __expf(-2.f * ax);
  float r = (1.f - t) * __builtin_amdgcn_rcpf(1.f + t);
  return copysignf(r, x);
}

// ---------------- K1: feature preparation ----------------

__device__ __forceinline__ void norm_hand(const float* __restrict__ xp, float* __restrict__ fp,
                                          int p0, int refp) {
  float rx = xp[2 * refp], ry = xp[2 * refp + 1];
  float px[21], py[21];
  float minx = 1e30f, maxx = -1e30f, miny = 1e30f, maxy = -1e30f;
#pragma unroll
  for (int i = 0; i < 21; ++i) {
    float ax = xp[2 * (p0 + i)] - rx;
    float ay = xp[2 * (p0 + i) + 1] - ry;
    px[i] = ax; py[i] = ay;
    minx = fminf(minx, ax); maxx = fmaxf(maxx, ax);
    miny = fminf(miny, ay); maxy = fmaxf(maxy, ay);
  }
  float s = fmaxf(maxx - minx, maxy - miny);
  if (s == 0.f) s = 1.f;
  float inv = 1.f / s;
#pragma unroll
  for (int i = 0; i < 21; ++i) {
    fp[2 * i] = px[i] * inv;
    fp[2 * i + 1] = py[i] * inv;
  }
}

__device__ __forceinline__ void norm_arm(const float* __restrict__ xp, float* __restrict__ fp,
                                         int a, int b, int c) {
  float rx = xp[0], ry = xp[1];  // ref = point 0 (center)
  float x0 = xp[2 * a] - rx, y0 = xp[2 * a + 1] - ry;
  float x1 = xp[2 * b] - rx, y1 = xp[2 * b + 1] - ry;
  float x2 = xp[2 * c] - rx, y2 = xp[2 * c + 1] - ry;
  float w = fmaxf(fmaxf(x0, x1), x2) - fminf(fminf(x0, x1), x2);
  float h = fmaxf(fmaxf(y0, y1), y2) - fminf(fminf(y0, y1), y2);
  float s = fmaxf(w, h);
  if (s == 0.f) s = 1.f;
  float inv = 1.f / s;
  fp[0] = x0 * inv; fp[1] = y0 * inv;
  fp[2] = x1 * inv; fp[3] = y1 * inv;
  fp[4] = x2 * inv; fp[5] = y2 * inv;
}

__global__ __launch_bounds__(256) void prep_kernel(const float* __restrict__ x,
                                                   float* __restrict__ feat) {
  int idx = blockIdx.x * 256 + threadIdx.x;
  if (idx >= BATCH * TLEN) return;
  const float* xp = x + (size_t)idx * XF;
  float* fp = feat + (size_t)idx * NF;
  norm_hand(xp, fp + 0, 112, 10);   // right hand: pts 112..132, ref pt 10
  norm_arm (xp, fp + 42, 6, 8, 10); // right arm: pts (6,8,10), ref center
  norm_hand(xp, fp + 48, 91, 9);    // left hand: pts 91..111, ref pt 9
  norm_arm (xp, fp + 90, 5, 7, 9);  // left arm: pts (5,7,9), ref center
}

// ---------------- K2: LSTM recurrence ----------------
// Quad-gate layout: thread = (gate q, hidden j), gate row = q*H + j.
// The 4 gate pre-activations for hidden j live in lanes 4j..4j+3 of one
// wave -> __shfl exchange, c/h computed redundantly in-quad.
// h and xf double-buffered in LDS -> ONE barrier per step.
// Weights held in VGPRs (launch_bounds(256,2) raises cap to 256).

template <int H, int IN>
__device__ __forceinline__ void lstm_run(
    const float* __restrict__ wih_row,   // this thread's gate row (IN floats)
    const float* __restrict__ whh_row,   // this thread's gate row (H floats)
    float bias,
    const float* __restrict__ xf_g,      // global ptr: this thread's xf element at t=0
    bool stage,                          // does this thread stage an xf element
    float* sxf0, float* sxf1,            // staging dest element in each buffer
    const float* rxf0, const float* rxf1,// xf read base per buffer
    float* hs0, float* hs1,              // h write slot per buffer (writer only)
    bool writer,                         // q == 0
    const float* rh0, const float* rh1,  // h read base per buffer
    float* __restrict__ out_col,         // &combined[b][0][coloff + j] (writer only)
    int q, int lane4) {
  float wi[IN];
  float wh[H];
#pragma unroll
  for (int k = 0; k < IN; ++k) wi[k] = wih_row[k];
#pragma unroll
  for (int k = 0; k < H; ++k) wh[k] = whh_row[k];

  if (writer) *hs0 = 0.f;
  if (stage) *sxf0 = xf_g[0];
  float c = 0.f;
  __syncthreads();

  int buf = 0;
  for (int t = 0; t < TLEN; ++t) {
    // prefetch next step's xf early; consumed at end of step
    float pf = 0.f;
    if (stage && t + 1 < TLEN) pf = xf_g[(size_t)(t + 1) * NF];

    const float* xb = buf ? rxf1 : rxf0;
    const float* hb = buf ? rh1 : rh0;
    float s0 = bias, s1 = 0.f, s2 = 0.f, s3 = 0.f;
#pragma unroll
    for (int k = 0; k + 3 < IN; k += 4) {
      s0 += wi[k] * xb[k];
      s1 += wi[k + 1] * xb[k + 1];
      s2 += wi[k + 2] * xb[k + 2];
      s3 += wi[k + 3] * xb[k + 3];
    }
#pragma unroll
    for (int k = IN & ~3; k < IN; ++k) s0 += wi[k] * xb[k];
#pragma unroll
    for (int k = 0; k < H; k += 4) {
      s0 += wh[k] * hb[k];
      s1 += wh[k + 1] * hb[k + 1];
      s2 += wh[k + 2] * hb[k + 2];
      s3 += wh[k + 3] * hb[k + 3];
    }
    float s = (s0 + s1) + (s2 + s3);

    float a = (q == 2) ? fast_tanh(s) : fast_sigmoid(s);

    float gi = __shfl(a, lane4 + 0, 64);
    float gf = __shfl(a, lane4 + 1, 64);
    float gg = __shfl(a, lane4 + 2, 64);
    float go = __shfl(a, lane4 + 3, 64);

    c = gf * c + gi * gg;
    float h = go * fast_tanh(c);

    if (writer) {
      *(buf ? hs0 : hs1) = h;             // write OTHER buffer
      out_col[(size_t)t * HID] = h;
    }
    if (stage && t + 1 < TLEN) *(buf ? sxf0 : sxf1) = pf;
    __syncthreads();
    buf ^= 1;
  }
}

__global__ __launch_bounds__(256, 2) void lstm_kernel(
    const float* __restrict__ feat,
    const float* __restrict__ w0i, const float* __restrict__ w0h,
    const float* __restrict__ b0i, const float* __restrict__ b0h,
    const float* __restrict__ w1i, const float* __restrict__ w1h,
    const float* __restrict__ b1i, const float* __restrict__ b1h,
    const float* __restrict__ w2i, const float* __restrict__ w2h,
    const float* __restrict__ b2i, const float* __restrict__ b2h,
    const float* __restrict__ w3i, const float* __restrict__ w3h,
    const float* __restrict__ b3i, const float* __restrict__ b3h,
    float* __restrict__ combined) {
  __shared__ float sh_h[2][64];
  __shared__ float sh_xf[2][48];
  int b = blockIdx.x;
  int l = blockIdx.y;   // 0: right hand (H=64), 1: left hand (H=64), 2: both arms (H=32 x2)
  int tid = threadIdx.x;
  int lane4 = (tid & 63) & ~3;
  const float* fb = feat + (size_t)b * TLEN * NF;
  float* cb = combined + (size_t)b * TLEN * HID;

  if (l < 2) {
    const float* wih = l ? w2i : w0i;
    const float* whh = l ? w2h : w0h;
    const float* bi  = l ? b2i : b0i;
    const float* bh  = l ? b2h : b0h;
    int xoff = l ? 48 : 0;
    int coff = l ? 96 : 0;
    int q = tid & 3, j = tid >> 2;
    int row = q * 64 + j;
    bool stage = tid < 42;
    int ss = stage ? tid : 0;
    lstm_run<64, 42>(
        wih + (size_t)row * 42, whh + (size_t)row * 64, bi[row] + bh[row],
        fb + xoff + ss, stage,
        &sh_xf[0][ss], &sh_xf[1][ss],
        &sh_xf[0][0], &sh_xf[1][0],
        &sh_h[0][j], &sh_h[1][j], q == 0,
        &sh_h[0][0], &sh_h[1][0],
        cb + coff + j, q, lane4);
  } else {
    int u = tid >> 7;        // 0: right arm, 1: left arm
    int tl = tid & 127;
    const float* wih = u ? w3i : w1i;
    const float* whh = u ? w3h : w1h;
    const float* bi  = u ? b3i : b1i;
    const float* bh  = u ? b3h : b1h;
    int xoff = u ? 90 : 42;
    int coff = u ? 160 : 64;
    int q = tl & 3, j = tl >> 2;
    int row = q * 32 + j;
    bool stage = tl < 6;
    int ss = u * 6 + (stage ? tl : 0);
    lstm_run<32, 6>(
        wih + (size_t)row * 6, whh + (size_t)row * 32, bi[row] + bh[row],
        fb + xoff + (stage ? tl : 0), stage,
        &sh_xf[0][ss], &sh_xf[1][ss],
        &sh_xf[0][u * 6], &sh_xf[1][u * 6],
        &sh_h[0][u * 32 + j], &sh_h[1][u * 32 + j], q == 0,
        &sh_h[0][u * 32], &sh_h[1][u * 32],
        cb + coff + j, q, lane4);
  }
}

// ---------------- K3: attention + FC ----------------

__global__ __launch_bounds__(256) void attn_kernel(const float* __restrict__ combined,
                                                   const float* __restrict__ att_w,
                                                   const float* __restrict__ fc_w,
                                                   const float* __restrict__ fc_b,
                                                   float* __restrict__ dout) {
  __shared__ float sc[TLEN];
  __shared__ float aw[HID];
  __shared__ float ctx[HID];
  __shared__ float red[4];
  int b = blockIdx.x, tid = threadIdx.x;
  const float* cb = combined + (size_t)b * TLEN * HID;
  if (tid < HID) aw[tid] = att_w[tid];
  __syncthreads();

  float lmax = -1e30f;
  for (int t = tid; t < TLEN; t += 256) {
    const float* r = cb + (size_t)t * HID;
    float s0 = 0.f, s1 = 0.f, s2 = 0.f, s3 = 0.f;
#pragma unroll
    for (int h = 0; h < HID; h += 4) {
      s0 += aw[h] * r[h];
      s1 += aw[h + 1] * r[h + 1];
      s2 += aw[h + 2] * r[h + 2];
      s3 += aw[h + 3] * r[h + 3];
    }
    float s = (s0 + s1) + (s2 + s3);
    sc[t] = s;
    lmax = fmaxf(lmax, s);
  }
#pragma unroll
  for (int o = 32; o > 0; o >>= 1) lmax = fmaxf(lmax, __shfl_down(lmax, o, 64));
  if ((tid & 63) == 0) red[tid >> 6] = lmax;
  __syncthreads();
  float m = fmaxf(fmaxf(red[0], red[1]), fmaxf(red[2], red[3]));
  __syncthreads();

  float lsum = 0.f;
  for (int t = tid; t < TLEN; t += 256) {
    float e = expf(sc[t] - m);
    sc[t] = e;
    lsum += e;
  }
#pragma unroll
  for (int o = 32; o > 0; o >>= 1) lsum += __shfl_down(lsum, o, 64);
  if ((tid & 63) == 0) red[tid >> 6] = lsum;
  __syncthreads();
  float S = red[0] + red[1] + red[2] + red[3];
  float inv = 1.f / S;
  for (int t = tid; t < TLEN; t += 256) {
    float w = sc[t] * inv;
    sc[t] = w;
    dout[BATCH * NC + b * TLEN + t] = w;  // weights output (B,T,1)
  }
  __syncthreads();

  if (tid < HID) {
    float c0 = 0.f, c1 = 0.f, c2 = 0.f, c3 = 0.f;
#pragma unroll 4
    for (int t = 0; t < TLEN; t += 4) {
      c0 += sc[t] * cb[(size_t)t * HID + tid];
      c1 += sc[t + 1] * cb[(size_t)(t + 1) * HID + tid];
      c2 += sc[t + 2] * cb[(size_t)(t + 2) * HID + tid];
      c3 += sc[t + 3] * cb[(size_t)(t + 3) * HID + tid];
    }
    ctx[tid] = (c0 + c1) + (c2 + c3);
  }
  __syncthreads();

  if (tid < NC) {
    const float* wr = fc_w + (size_t)tid * HID;
    float s0 = fc_b[tid], s1 = 0.f, s2 = 0.f, s3 = 0.f;
#pragma unroll
    for (int h = 0; h < HID; h += 4) {
      s0 += ctx[h] * wr[h];
      s1 += ctx[h + 1] * wr[h + 1];
      s2 += ctx[h + 2] * wr[h + 2];
      s3 += ctx[h + 3] * wr[h + 3];
    }
    dout[b * NC + tid] = (s0 + s1) + (s2 + s3);  // logits (B,250)
  }
}

// ---------------- launcher ----------------

extern "C" void kernel_launch(void* const* d_in, const int* in_sizes, int n_in,
                              void* d_out, int out_size, void* d_ws, size_t ws_size,
                              hipStream_t stream) {
  const float* x = (const float*)d_in[0];
  const float* wih_rh = (const float*)d_in[1];
  const float* whh_rh = (const float*)d_in[2];
  const float* bih_rh = (const float*)d_in[3];
  const float* bhh_rh = (const float*)d_in[4];
  const float* wih_ra = (const float*)d_in[5];
  const float* whh_ra = (const float*)d_in[6];
  const float* bih_ra = (const float*)d_in[7];
  const float* bhh_ra = (const float*)d_in[8];
  const float* wih_lh = (const float*)d_in[9];
  const float* whh_lh = (const float*)d_in[10];
  const float* bih_lh = (const float*)d_in[11];
  const float* bhh_lh = (const float*)d_in[12];
  const float* wih_la = (const float*)d_in[13];
  const float* whh_la = (const float*)d_in[14];
  const float* bih_la = (const float*)d_in[15];
  const float* bhh_la = (const float*)d_in[16];
  const float* att_w = (const float*)d_in[17];
  const float* fc_w = (const float*)d_in[18];
  const float* fc_b = (const float*)d_in[19];

  float* feat = (float*)d_ws;                         // 128*512*96 floats = 25.2 MB
  float* combined = feat + (size_t)BATCH * TLEN * NF; // 128*512*192 floats = 50.3 MB

  prep_kernel<<<dim3((BATCH * TLEN + 255) / 256), 256, 0, stream>>>(x, feat);
  lstm_kernel<<<dim3(BATCH, 3), 256, 0, stream>>>(
      feat,
      wih_rh, whh_rh, bih_rh, bhh_rh,
      wih_ra, whh_ra, bih_ra, bhh_ra,
      wih_lh, whh_lh, bih_lh, bhh_lh,
      wih_la, whh_la, bih_la, bhh_la,
      combined);
  attn_kernel<<<dim3(BATCH), 256, 0, stream>>>(combined, att_w, fc_w, fc_b, (float*)d_out);
}

// Round 4
// 691.040 us; speedup vs baseline: 1.0998x; 1.0998x over previous
//
#include <hip/hip_runtime.h>
#include <math.h>

#define BATCH 128
#define TLEN 512
#define XF 266
#define NF 96
#define HID 192
#define NC 250

typedef __attribute__((ext_vector_type(8))) short short8;
typedef __attribute__((ext_vector_type(4))) float float4v;

// fp32 -> bf16 (RNE)
__device__ __forceinline__ unsigned short f2bf(float f) {
  unsigned u = __float_as_uint(f);
  u += 0x7FFF + ((u >> 16) & 1);
  return (unsigned short)(u >> 16);
}

__device__ __forceinline__ float fast_sigmoid(float x) {
  float t = __expf(-x);
  return __builtin_amdgcn_rcpf(1.f + t);
}
__device__ __forceinline__ float fast_tanh(float x) {
  float ax = fabsf(x);
  float t = __expf(-2.f * ax);
  float r = (1.f - t) * __builtin_amdgcn_rcpf(1.f + t);
  return copysignf(r, x);
}

// ---------------- K1: feature preparation (writes bf16) ----------------

__device__ __forceinline__ void norm_hand(const float* __restrict__ xp,
                                          unsigned short* __restrict__ fp,
                                          int p0, int refp) {
  float rx = xp[2 * refp], ry = xp[2 * refp + 1];
  float px[21], py[21];
  float minx = 1e30f, maxx = -1e30f, miny = 1e30f, maxy = -1e30f;
#pragma unroll
  for (int i = 0; i < 21; ++i) {
    float ax = xp[2 * (p0 + i)] - rx;
    float ay = xp[2 * (p0 + i) + 1] - ry;
    px[i] = ax; py[i] = ay;
    minx = fminf(minx, ax); maxx = fmaxf(maxx, ax);
    miny = fminf(miny, ay); maxy = fmaxf(maxy, ay);
  }
  float s = fmaxf(maxx - minx, maxy - miny);
  if (s == 0.f) s = 1.f;
  float inv = 1.f / s;
#pragma unroll
  for (int i = 0; i < 21; ++i) {
    fp[2 * i] = f2bf(px[i] * inv);
    fp[2 * i + 1] = f2bf(py[i] * inv);
  }
}

__device__ __forceinline__ void norm_arm(const float* __restrict__ xp,
                                         unsigned short* __restrict__ fp,
                                         int a, int b, int c) {
  float rx = xp[0], ry = xp[1];
  float x0 = xp[2 * a] - rx, y0 = xp[2 * a + 1] - ry;
  float x1 = xp[2 * b] - rx, y1 = xp[2 * b + 1] - ry;
  float x2 = xp[2 * c] - rx, y2 = xp[2 * c + 1] - ry;
  float w = fmaxf(fmaxf(x0, x1), x2) - fminf(fminf(x0, x1), x2);
  float h = fmaxf(fmaxf(y0, y1), y2) - fminf(fminf(y0, y1), y2);
  float s = fmaxf(w, h);
  if (s == 0.f) s = 1.f;
  float inv = 1.f / s;
  fp[0] = f2bf(x0 * inv); fp[1] = f2bf(y0 * inv);
  fp[2] = f2bf(x1 * inv); fp[3] = f2bf(y1 * inv);
  fp[4] = f2bf(x2 * inv); fp[5] = f2bf(y2 * inv);
}

__global__ __launch_bounds__(256) void prep_kernel(const float* __restrict__ x,
                                                   unsigned short* __restrict__ feat) {
  int idx = blockIdx.x * 256 + threadIdx.x;
  if (idx >= BATCH * TLEN) return;
  const float* xp = x + (size_t)idx * XF;
  unsigned short* fp = feat + (size_t)idx * NF;
  norm_hand(xp, fp + 0, 112, 10);   // right hand -> [0,42)
  norm_arm (xp, fp + 42, 6, 8, 10); // right arm  -> [42,48)
  norm_hand(xp, fp + 48, 91, 9);    // left hand  -> [48,90)
  norm_arm (xp, fp + 90, 5, 7, 9);  // left arm   -> [90,96)
}

// ---------------- K1b: weight packing -> bf16 B^T [G][K] ----------------
// Hands: K=128 = [wih(42) | 0(22) | whh(64)], G=256.
// Arms:  K=64  = [wih(6)  | 0(26) | whh(32)], G=128.

__global__ __launch_bounds__(256) void pack_kernel(
    const float* __restrict__ wi_rh, const float* __restrict__ wh_rh,
    const float* __restrict__ wi_ra, const float* __restrict__ wh_ra,
    const float* __restrict__ wi_lh, const float* __restrict__ wh_lh,
    const float* __restrict__ wi_la, const float* __restrict__ wh_la,
    unsigned short* __restrict__ bt_rh, unsigned short* __restrict__ bt_ra,
    unsigned short* __restrict__ bt_lh, unsigned short* __restrict__ bt_la) {
  int g = threadIdx.x;
  // hands (g < 256)
  for (int k = 0; k < 128; ++k) {
    float v0 = (k < 42) ? wi_rh[g * 42 + k] : (k < 64 ? 0.f : wh_rh[g * 64 + (k - 64)]);
    float v1 = (k < 42) ? wi_lh[g * 42 + k] : (k < 64 ? 0.f : wh_lh[g * 64 + (k - 64)]);
    bt_rh[g * 128 + k] = f2bf(v0);
    bt_lh[g * 128 + k] = f2bf(v1);
  }
  if (g < 128) {
    for (int k = 0; k < 64; ++k) {
      float v0 = (k < 6) ? wi_ra[g * 6 + k] : (k < 32 ? 0.f : wh_ra[g * 32 + (k - 32)]);
      float v1 = (k < 6) ? wi_la[g * 6 + k] : (k < 32 ? 0.f : wh_la[g * 32 + (k - 32)]);
      bt_ra[g * 64 + k] = f2bf(v0);
      bt_la[g * 64 + k] = f2bf(v1);
    }
  }
}

// ---------------- K2: MFMA LSTM recurrence ----------------
// One block = one (LSTM, batch-tile). A = [x_t | 0 | h_t] bf16 in LDS,
// double-buffered (1 barrier/step). B (weights) in register fragments,
// loaded once. Wave owns all 4 gate tiles for one 16-j group -> i/f/g/o
// land in same lane & reg; activations fully in-register, no shuffles.
// MFMA 16x16x32 bf16: A[m=lane&15][k=quad*8+j]; C/D col=lane&15,
// row=quad*4+reg (verified mappings, cdna_hip_programming.md §3).

template <int H, int CH, int IN, int STR, int MB, int NSTAGE>
__device__ __forceinline__ void lstm_core(
    unsigned short* __restrict__ Ab0, unsigned short* __restrict__ Ab1,
    const unsigned short* __restrict__ Bt,
    const float* __restrict__ bi, const float* __restrict__ bh,
    const unsigned short* __restrict__ feat16, int xoff, int b0,
    float* __restrict__ comb,   // combined + coff
    int mrow0, int j0) {
  constexpr int K = CH * 32;
  constexpr int HOFF = K - H;
  int tid = threadIdx.x;
  int lane = tid & 63;
  int n = lane & 15;
  int quad = lane >> 4;

  // B fragments + bias (loaded once; registers)
  short8 Vb[4][CH];
  float bias[4];
#pragma unroll
  for (int q = 0; q < 4; ++q) {
    int g = q * H + j0 + n;
    bias[q] = bi[g] + bh[g];
#pragma unroll
    for (int c = 0; c < CH; ++c)
      Vb[q][c] = *(const short8*)(Bt + (size_t)g * K + c * 32 + quad * 8);
  }

  // x staging assignments (each thread stages <= NSTAGE elements)
  int sm[NSTAGE], sk[NSTAGE];
  bool sv[NSTAGE];
#pragma unroll
  for (int p = 0; p < NSTAGE; ++p) {
    int e = tid + p * 256;
    sv[p] = e < MB * IN;
    int ee = sv[p] ? e : 0;
    sm[p] = ee / IN;
    sk[p] = ee % IN;
  }

  // init: zero pad+h region in both buffers; stage x_0 into buf0
  for (int idx = tid; idx < MB * (K - IN); idx += 256) {
    int m = idx / (K - IN), k = IN + idx % (K - IN);
    Ab0[m * STR + k] = 0;
    Ab1[m * STR + k] = 0;
  }
#pragma unroll
  for (int p = 0; p < NSTAGE; ++p)
    if (sv[p])
      Ab0[sm[p] * STR + sk[p]] =
          feat16[((size_t)(b0 + sm[p]) * TLEN) * NF + xoff + sk[p]];
  float4v cc = {0.f, 0.f, 0.f, 0.f};
  __syncthreads();

  unsigned short* Ar = Ab0;  // read buffer
  unsigned short* Aw = Ab1;  // write buffer (next step)
  int arow = mrow0 + n;
  int j = j0 + n;

  for (int t = 0; t < TLEN; ++t) {
    // prefetch x_{t+1} (uniform guard)
    unsigned short xv[NSTAGE];
    bool doPf = (t + 1 < TLEN);
    if (doPf) {
#pragma unroll
      for (int p = 0; p < NSTAGE; ++p)
        if (sv[p])
          xv[p] = feat16[((size_t)(b0 + sm[p]) * TLEN + (t + 1)) * NF + xoff + sk[p]];
    }

    // A fragments from LDS
    short8 Va[CH];
#pragma unroll
    for (int c = 0; c < CH; ++c)
      Va[c] = *(const short8*)(Ar + arow * STR + c * 32 + quad * 8);

    // gates = A @ B + bias
    float4v acc[4];
#pragma unroll
    for (int q = 0; q < 4; ++q) {
      acc[q] = (float4v){bias[q], bias[q], bias[q], bias[q]};
#pragma unroll
      for (int c = 0; c < CH; ++c)
        acc[q] = __builtin_amdgcn_mfma_f32_16x16x32_bf16(Va[c], Vb[q][c], acc[q], 0, 0, 0);
    }

    // activations + state update; h -> LDS (bf16) + combined (fp32)
#pragma unroll
    for (int r = 0; r < 4; ++r) {
      float gi = fast_sigmoid(acc[0][r]);
      float gf = fast_sigmoid(acc[1][r]);
      float gg = fast_tanh(acc[2][r]);
      float go = fast_sigmoid(acc[3][r]);
      float cv = gf * cc[r] + gi * gg;
      cc[r] = cv;
      float h = go * fast_tanh(cv);
      int m = mrow0 + quad * 4 + r;
      Aw[m * STR + HOFF + j] = f2bf(h);
      comb[((size_t)(b0 + m) * TLEN + t) * HID + j] = h;
    }

    // store staged x_{t+1}
    if (doPf) {
#pragma unroll
      for (int p = 0; p < NSTAGE; ++p)
        if (sv[p]) Aw[sm[p] * STR + sk[p]] = xv[p];
    }
    __syncthreads();
    unsigned short* tmp = Ar; Ar = Aw; Aw = tmp;
  }
}

__global__ __launch_bounds__(256, 1) void lstm_kernel(
    const unsigned short* __restrict__ feat16,
    const unsigned short* __restrict__ bt_rh, const unsigned short* __restrict__ bt_ra,
    const unsigned short* __restrict__ bt_lh, const unsigned short* __restrict__ bt_la,
    const float* __restrict__ b0i, const float* __restrict__ b0h,
    const float* __restrict__ b1i, const float* __restrict__ b1h,
    const float* __restrict__ b2i, const float* __restrict__ b2h,
    const float* __restrict__ b3i, const float* __restrict__ b3h,
    float* __restrict__ combined) {
  __shared__ __align__(16) unsigned short A0[2304];
  __shared__ __align__(16) unsigned short A1[2304];
  int blk = blockIdx.x;
  int wave = threadIdx.x >> 6;
  if (blk < 8) {        // right hand: H=64, batches [16*blk, +16)
    lstm_core<64, 4, 42, 136, 16, 3>(A0, A1, bt_rh, b0i, b0h, feat16, 0, blk * 16,
                                     combined + 0, 0, 16 * wave);
  } else if (blk < 16) {  // left hand
    lstm_core<64, 4, 42, 136, 16, 3>(A0, A1, bt_lh, b2i, b2h, feat16, 48, (blk - 8) * 16,
                                     combined + 96, 0, 16 * wave);
  } else if (blk < 20) {  // right arm: H=32, batches [32*(blk-16), +32)
    lstm_core<32, 2, 6, 72, 32, 1>(A0, A1, bt_ra, b1i, b1h, feat16, 42, (blk - 16) * 32,
                                   combined + 64, 16 * (wave >> 1), 16 * (wave & 1));
  } else {                // left arm
    lstm_core<32, 2, 6, 72, 32, 1>(A0, A1, bt_la, b3i, b3h, feat16, 90, (blk - 20) * 32,
                                   combined + 160, 16 * (wave >> 1), 16 * (wave & 1));
  }
}

// ---------------- K3: attention + FC ----------------

__global__ __launch_bounds__(256) void attn_kernel(const float* __restrict__ combined,
                                                   const float* __restrict__ att_w,
                                                   const float* __restrict__ fc_w,
                                                   const float* __restrict__ fc_b,
                                                   float* __restrict__ dout) {
  __shared__ float sc[TLEN];
  __shared__ float aw[HID];
  __shared__ float ctx[HID];
  __shared__ float red[4];
  int b = blockIdx.x, tid = threadIdx.x;
  const float* cb = combined + (size_t)b * TLEN * HID;
  if (tid < HID) aw[tid] = att_w[tid];
  __syncthreads();

  float lmax = -1e30f;
  for (int t = tid; t < TLEN; t += 256) {
    const float* r = cb + (size_t)t * HID;
    float s0 = 0.f, s1 = 0.f, s2 = 0.f, s3 = 0.f;
#pragma unroll
    for (int h = 0; h < HID; h += 4) {
      s0 += aw[h] * r[h];
      s1 += aw[h + 1] * r[h + 1];
      s2 += aw[h + 2] * r[h + 2];
      s3 += aw[h + 3] * r[h + 3];
    }
    float s = (s0 + s1) + (s2 + s3);
    sc[t] = s;
    lmax = fmaxf(lmax, s);
  }
#pragma unroll
  for (int o = 32; o > 0; o >>= 1) lmax = fmaxf(lmax, __shfl_down(lmax, o, 64));
  if ((tid & 63) == 0) red[tid >> 6] = lmax;
  __syncthreads();
  float m = fmaxf(fmaxf(red[0], red[1]), fmaxf(red[2], red[3]));
  __syncthreads();

  float lsum = 0.f;
  for (int t = tid; t < TLEN; t += 256) {
    float e = expf(sc[t] - m);
    sc[t] = e;
    lsum += e;
  }
#pragma unroll
  for (int o = 32; o > 0; o >>= 1) lsum += __shfl_down(lsum, o, 64);
  if ((tid & 63) == 0) red[tid >> 6] = lsum;
  __syncthreads();
  float S = red[0] + red[1] + red[2] + red[3];
  float inv = 1.f / S;
  for (int t = tid; t < TLEN; t += 256) {
    float w = sc[t] * inv;
    sc[t] = w;
    dout[BATCH * NC + b * TLEN + t] = w;  // weights output (B,T,1)
  }
  __syncthreads();

  if (tid < HID) {
    float c0 = 0.f, c1 = 0.f, c2 = 0.f, c3 = 0.f;
#pragma unroll 4
    for (int t = 0; t < TLEN; t += 4) {
      c0 += sc[t] * cb[(size_t)t * HID + tid];
      c1 += sc[t + 1] * cb[(size_t)(t + 1) * HID + tid];
      c2 += sc[t + 2] * cb[(size_t)(t + 2) * HID + tid];
      c3 += sc[t + 3] * cb[(size_t)(t + 3) * HID + tid];
    }
    ctx[tid] = (c0 + c1) + (c2 + c3);
  }
  __syncthreads();

  if (tid < NC) {
    const float* wr = fc_w + (size_t)tid * HID;
    float s0 = fc_b[tid], s1 = 0.f, s2 = 0.f, s3 = 0.f;
#pragma unroll
    for (int h = 0; h < HID; h += 4) {
      s0 += ctx[h] * wr[h];
      s1 += ctx[h + 1] * wr[h + 1];
      s2 += ctx[h + 2] * wr[h + 2];
      s3 += ctx[h + 3] * wr[h + 3];
    }
    dout[b * NC + tid] = (s0 + s1) + (s2 + s3);  // logits (B,250)
  }
}

// ---------------- launcher ----------------

extern "C" void kernel_launch(void* const* d_in, const int* in_sizes, int n_in,
                              void* d_out, int out_size, void* d_ws, size_t ws_size,
                              hipStream_t stream) {
  const float* x = (const float*)d_in[0];
  const float* wih_rh = (const float*)d_in[1];
  const float* whh_rh = (const float*)d_in[2];
  const float* bih_rh = (const float*)d_in[3];
  const float* bhh_rh = (const float*)d_in[4];
  const float* wih_ra = (const float*)d_in[5];
  const float* whh_ra = (const float*)d_in[6];
  const float* bih_ra = (const float*)d_in[7];
  const float* bhh_ra = (const float*)d_in[8];
  const float* wih_lh = (const float*)d_in[9];
  const float* whh_lh = (const float*)d_in[10];
  const float* bih_lh = (const float*)d_in[11];
  const float* bhh_lh = (const float*)d_in[12];
  const float* wih_la = (const float*)d_in[13];
  const float* whh_la = (const float*)d_in[14];
  const float* bih_la = (const float*)d_in[15];
  const float* bhh_la = (const float*)d_in[16];
  const float* att_w = (const float*)d_in[17];
  const float* fc_w = (const float*)d_in[18];
  const float* fc_b = (const float*)d_in[19];

  // ws layout (~63.1 MB total)
  unsigned short* feat16 = (unsigned short*)d_ws;                 // 128*512*96*2  = 12,582,912 B
  float* combined = (float*)((char*)d_ws + 12582912);             // 128*512*192*4 = 50,331,648 B
  unsigned short* bt_rh = (unsigned short*)((char*)d_ws + 62914560);  // 256*128*2
  unsigned short* bt_lh = bt_rh + 256 * 128;                          // 256*128*2
  unsigned short* bt_ra = bt_lh + 256 * 128;                          // 128*64*2
  unsigned short* bt_la = bt_ra + 128 * 64;                           // 128*64*2

  prep_kernel<<<dim3((BATCH * TLEN + 255) / 256), 256, 0, stream>>>(x, feat16);
  pack_kernel<<<dim3(1), 256, 0, stream>>>(
      wih_rh, whh_rh, wih_ra, whh_ra, wih_lh, whh_lh, wih_la, whh_la,
      bt_rh, bt_ra, bt_lh, bt_la);
  lstm_kernel<<<dim3(24), 256, 0, stream>>>(
      feat16, bt_rh, bt_ra, bt_lh, bt_la,
      bih_rh, bhh_rh, bih_ra, bhh_ra, bih_lh, bhh_lh, bih_la, bhh_la,
      combined);
  attn_kernel<<<dim3(BATCH), 256, 0, stream>>>(combined, att_w, fc_w, fc_b, (float*)d_out);
}

// Round 5
// 596.748 us; speedup vs baseline: 1.2736x; 1.1580x over previous
//
#include <hip/hip_runtime.h>
#include <math.h>

#define BATCH 128
#define TLEN 512
#define XF 266
#define HID 192
#define NC 250

typedef __attribute__((ext_vector_type(8))) short short8;
typedef __attribute__((ext_vector_type(4))) float float4v;

// fp32 -> bf16 (RNE)
__device__ __forceinline__ unsigned short f2bf(float f) {
  unsigned u = __float_as_uint(f);
  u += 0x7FFF + ((u >> 16) & 1);
  return (unsigned short)(u >> 16);
}

__device__ __forceinline__ float fast_sigmoid(float x) {
  float t = __expf(-x);
  return __builtin_amdgcn_rcpf(1.f + t);
}
// tanh(x) = 2*sigmoid(2x)-1 ; saturates correctly at +-1, branch-free
__device__ __forceinline__ float fast_tanh(float x) {
  float t = __expf(-2.f * x);
  return fmaf(2.f, __builtin_amdgcn_rcpf(1.f + t), -1.f);
}

// LDS-only barrier: does NOT drain vmcnt (global stores keep flying).
__device__ __forceinline__ void lds_barrier() {
  asm volatile("s_waitcnt lgkmcnt(0)\n\ts_barrier" ::: "memory");
}

// ---------------- K1: feature prep -> per-LSTM padded bf16 layouts --------
// featH*: [tile8][t512][m16][48]  (42 real + 6 zero)
// featA*: [tile4][t512][m32][8]   (6 real + 2 zero)

__device__ __forceinline__ void norm_hand(const float* __restrict__ xp,
                                          unsigned short* __restrict__ fp,
                                          int p0, int refp) {
  float rx = xp[2 * refp], ry = xp[2 * refp + 1];
  float px[21], py[21];
  float minx = 1e30f, maxx = -1e30f, miny = 1e30f, maxy = -1e30f;
#pragma unroll
  for (int i = 0; i < 21; ++i) {
    float ax = xp[2 * (p0 + i)] - rx;
    float ay = xp[2 * (p0 + i) + 1] - ry;
    px[i] = ax; py[i] = ay;
    minx = fminf(minx, ax); maxx = fmaxf(maxx, ax);
    miny = fminf(miny, ay); maxy = fmaxf(maxy, ay);
  }
  float s = fmaxf(maxx - minx, maxy - miny);
  if (s == 0.f) s = 1.f;
  float inv = 1.f / s;
#pragma unroll
  for (int i = 0; i < 21; ++i) {
    fp[2 * i] = f2bf(px[i] * inv);
    fp[2 * i + 1] = f2bf(py[i] * inv);
  }
  fp[42] = 0; fp[43] = 0; fp[44] = 0; fp[45] = 0; fp[46] = 0; fp[47] = 0;
}

__device__ __forceinline__ void norm_arm(const float* __restrict__ xp,
                                         unsigned short* __restrict__ fp,
                                         int a, int b, int c) {
  float rx = xp[0], ry = xp[1];
  float x0 = xp[2 * a] - rx, y0 = xp[2 * a + 1] - ry;
  float x1 = xp[2 * b] - rx, y1 = xp[2 * b + 1] - ry;
  float x2 = xp[2 * c] - rx, y2 = xp[2 * c + 1] - ry;
  float w = fmaxf(fmaxf(x0, x1), x2) - fminf(fminf(x0, x1), x2);
  float h = fmaxf(fmaxf(y0, y1), y2) - fminf(fminf(y0, y1), y2);
  float s = fmaxf(w, h);
  if (s == 0.f) s = 1.f;
  float inv = 1.f / s;
  fp[0] = f2bf(x0 * inv); fp[1] = f2bf(y0 * inv);
  fp[2] = f2bf(x1 * inv); fp[3] = f2bf(y1 * inv);
  fp[4] = f2bf(x2 * inv); fp[5] = f2bf(y2 * inv);
  fp[6] = 0; fp[7] = 0;
}

__global__ __launch_bounds__(256) void prep_kernel(
    const float* __restrict__ x,
    unsigned short* __restrict__ fHR, unsigned short* __restrict__ fHL,
    unsigned short* __restrict__ fAR, unsigned short* __restrict__ fAL) {
  int idx = blockIdx.x * 256 + threadIdx.x;
  if (idx >= BATCH * TLEN) return;
  int b = idx >> 9, t = idx & 511;
  const float* xp = x + (size_t)idx * XF;
  size_t hoff = (((size_t)(b >> 4) * TLEN + t) * 16 + (b & 15)) * 48;
  size_t aoff = (((size_t)(b >> 5) * TLEN + t) * 32 + (b & 31)) * 8;
  norm_hand(xp, fHR + hoff, 112, 10);  // right hand, ref pt 10
  norm_hand(xp, fHL + hoff, 91, 9);    // left hand, ref pt 9
  norm_arm (xp, fAR + aoff, 6, 8, 10); // right arm
  norm_arm (xp, fAL + aoff, 5, 7, 9);  // left arm
}

// ---------------- K1b: weight packing -> bf16 B^T [G][K] ------------------
// Hands K=128 = [wih(42)|0(22)|whh(64)]; Arms K=64 = [wih(6)|0(26)|whh(32)]

__global__ __launch_bounds__(256) void pack_kernel(
    const float* __restrict__ wi_rh, const float* __restrict__ wh_rh,
    const float* __restrict__ wi_ra, const float* __restrict__ wh_ra,
    const float* __restrict__ wi_lh, const float* __restrict__ wh_lh,
    const float* __restrict__ wi_la, const float* __restrict__ wh_la,
    unsigned short* __restrict__ bt_rh, unsigned short* __restrict__ bt_ra,
    unsigned short* __restrict__ bt_lh, unsigned short* __restrict__ bt_la) {
  int blk = blockIdx.x, tid = threadIdx.x;
  if (blk == 0) {
    for (int i = tid; i < 256 * 128; i += 256) {
      int g = i >> 7, k = i & 127;
      float v = (k < 42) ? wi_rh[g * 42 + k] : (k < 64 ? 0.f : wh_rh[g * 64 + (k - 64)]);
      bt_rh[i] = f2bf(v);
    }
  } else if (blk == 1) {
    for (int i = tid; i < 256 * 128; i += 256) {
      int g = i >> 7, k = i & 127;
      float v = (k < 42) ? wi_lh[g * 42 + k] : (k < 64 ? 0.f : wh_lh[g * 64 + (k - 64)]);
      bt_lh[i] = f2bf(v);
    }
  } else if (blk == 2) {
    for (int i = tid; i < 128 * 64; i += 256) {
      int g = i >> 6, k = i & 63;
      float v = (k < 6) ? wi_ra[g * 6 + k] : (k < 32 ? 0.f : wh_ra[g * 32 + (k - 32)]);
      bt_ra[i] = f2bf(v);
    }
  } else {
    for (int i = tid; i < 128 * 64; i += 256) {
      int g = i >> 6, k = i & 63;
      float v = (k < 6) ? wi_la[g * 6 + k] : (k < 32 ? 0.f : wh_la[g * 32 + (k - 32)]);
      bt_la[i] = f2bf(v);
    }
  }
}

// ---------------- K2: MFMA LSTM recurrence --------------------------------
// A row layout (hands, STR=136): [x 0..47 staged | 0 48..63 | h 64..127]
// A row layout (arms,  STR=72):  [x 0..7 staged  | 0 8..31  | h 32..63]
// Double-buffered, ONE lds-only barrier/step (no vmcnt drain).
// Staging: 1 dwordx4 global load + 1 ds_write_b128 per active thread.

template <int H, int CH, int STR, int MB, int SCH>
__device__ __forceinline__ void lstm_core(
    unsigned short* __restrict__ Ab0, unsigned short* __restrict__ Ab1,
    const unsigned short* __restrict__ Bt,
    const float* __restrict__ bi, const float* __restrict__ bh,
    const unsigned short* __restrict__ featp,  // + tile*TLEN*MB*SCH*8
    float* __restrict__ comb,                   // combined + coff
    int b0, int mrow0, int j0) {
  constexpr int K = CH * 32;
  constexpr int HOFF = K - H;
  constexpr int XSH = MB * SCH * 8;  // shorts per t-slice
  int tid = threadIdx.x;
  int lane = tid & 63, n = lane & 15, quad = lane >> 4;

  // B fragments + bias (registers, loaded once)
  short8 Vb[4][CH];
  float bias[4];
#pragma unroll
  for (int q = 0; q < 4; ++q) {
    int g = q * H + j0 + n;
    bias[q] = bi[g] + bh[g];
#pragma unroll
    for (int c = 0; c < CH; ++c)
      Vb[q][c] = *(const short8*)(Bt + (size_t)g * K + c * 32 + quad * 8);
  }

  // zero both buffers (pads + initial h=0), stage x_0 into buf0
  for (int i = tid; i < MB * STR; i += 256) { Ab0[i] = 0; Ab1[i] = 0; }
  bool st = tid < MB * SCH;
  int sm = tid / SCH, sc8 = tid % SCH;
  unsigned short* xd0 = Ab0 + sm * STR + sc8 * 8;
  unsigned short* xd1 = Ab1 + sm * STR + sc8 * 8;
  const unsigned short* fp = featp + tid * 8;
  if (st) *(short8*)xd0 = *(const short8*)fp;
  fp += XSH;  // -> t=1 slice
  float4v cc = {0.f, 0.f, 0.f, 0.f};
  __syncthreads();

  // per-buffer read/write bases
  const unsigned short* ard0 = Ab0 + (mrow0 + n) * STR;
  const unsigned short* ard1 = Ab1 + (mrow0 + n) * STR;
  unsigned short* hw0 = Ab0 + (mrow0 + quad * 4) * STR + HOFF + j0 + n;
  unsigned short* hw1 = Ab1 + (mrow0 + quad * 4) * STR + HOFF + j0 + n;

  // comb store pointers (incremented by HID per step)
  float* cp0 = comb + ((size_t)(b0 + mrow0 + quad * 4 + 0) * TLEN) * HID + j0 + n;
  float* cp1 = comb + ((size_t)(b0 + mrow0 + quad * 4 + 1) * TLEN) * HID + j0 + n;
  float* cp2 = comb + ((size_t)(b0 + mrow0 + quad * 4 + 2) * TLEN) * HID + j0 + n;
  float* cp3 = comb + ((size_t)(b0 + mrow0 + quad * 4 + 3) * TLEN) * HID + j0 + n;

  for (int t = 0; t < TLEN; ++t) {
    int par = t & 1;
    // prefetch x_{t+1}
    short8 xv;
    bool doPf = st && (t + 1 < TLEN);
    if (doPf) xv = *(const short8*)fp;
    fp += XSH;

    // A fragments
    const unsigned short* ard = par ? ard1 : ard0;
    short8 Va[CH];
#pragma unroll
    for (int c = 0; c < CH; ++c)
      Va[c] = *(const short8*)(ard + c * 32 + quad * 8);

    // gates = A @ B + bias
    float4v acc[4];
#pragma unroll
    for (int q = 0; q < 4; ++q) {
      acc[q] = (float4v){bias[q], bias[q], bias[q], bias[q]};
#pragma unroll
      for (int c = 0; c < CH; ++c)
        acc[q] = __builtin_amdgcn_mfma_f32_16x16x32_bf16(Va[c], Vb[q][c], acc[q], 0, 0, 0);
    }

    // activations + state; h -> other LDS buffer (bf16) + combined (fp32)
    unsigned short* hw = par ? hw0 : hw1;  // write the buffer we'll read next
#pragma unroll
    for (int r = 0; r < 4; ++r) {
      float gi = fast_sigmoid(acc[0][r]);
      float gf = fast_sigmoid(acc[1][r]);
      float gg = fast_tanh(acc[2][r]);
      float go = fast_sigmoid(acc[3][r]);
      float cv = fmaf(gf, cc[r], gi * gg);
      cc[r] = cv;
      float h = go * fast_tanh(cv);
      hw[r * STR] = f2bf(h);
      if (r == 0) { *cp0 = h; cp0 += HID; }
      else if (r == 1) { *cp1 = h; cp1 += HID; }
      else if (r == 2) { *cp2 = h; cp2 += HID; }
      else { *cp3 = h; cp3 += HID; }
    }

    if (doPf) *(short8*)(par ? xd0 : xd1) = xv;
    lds_barrier();
  }
}

__global__ __launch_bounds__(256, 1) void lstm_kernel(
    const unsigned short* __restrict__ fHR, const unsigned short* __restrict__ fHL,
    const unsigned short* __restrict__ fAR, const unsigned short* __restrict__ fAL,
    const unsigned short* __restrict__ bt_rh, const unsigned short* __restrict__ bt_ra,
    const unsigned short* __restrict__ bt_lh, const unsigned short* __restrict__ bt_la,
    const float* __restrict__ b0i, const float* __restrict__ b0h,
    const float* __restrict__ b1i, const float* __restrict__ b1h,
    const float* __restrict__ b2i, const float* __restrict__ b2h,
    const float* __restrict__ b3i, const float* __restrict__ b3h,
    float* __restrict__ combined) {
  __shared__ __align__(16) unsigned short A0[2304];
  __shared__ __align__(16) unsigned short A1[2304];
  int blk = blockIdx.x;
  int wave = threadIdx.x >> 6;
  if (blk < 8) {          // right hand: H=64, batches [16*blk,+16)
    lstm_core<64, 4, 136, 16, 6>(A0, A1, bt_rh, b0i, b0h,
                                 fHR + (size_t)blk * TLEN * 768,
                                 combined + 0, blk * 16, 0, 16 * wave);
  } else if (blk < 16) {  // left hand
    int tl = blk - 8;
    lstm_core<64, 4, 136, 16, 6>(A0, A1, bt_lh, b2i, b2h,
                                 fHL + (size_t)tl * TLEN * 768,
                                 combined + 96, tl * 16, 0, 16 * wave);
  } else if (blk < 20) {  // right arm: H=32, batches [32*(blk-16),+32)
    int tl = blk - 16;
    lstm_core<32, 2, 72, 32, 1>(A0, A1, bt_ra, b1i, b1h,
                                fAR + (size_t)tl * TLEN * 256,
                                combined + 64, tl * 32, 16 * (wave >> 1), 16 * (wave & 1));
  } else {                // left arm
    int tl = blk - 20;
    lstm_core<32, 2, 72, 32, 1>(A0, A1, bt_la, b3i, b3h,
                                fAL + (size_t)tl * TLEN * 256,
                                combined + 160, tl * 32, 16 * (wave >> 1), 16 * (wave & 1));
  }
}

// ---------------- K3: attention + FC (coalesced passes) -------------------

__global__ __launch_bounds__(256) void attn_kernel(const float* __restrict__ combined,
                                                   const float* __restrict__ att_w,
                                                   const float* __restrict__ fc_w,
                                                   const float* __restrict__ fc_b,
                                                   float* __restrict__ dout) {
  __shared__ float sc[TLEN];
  __shared__ float aw[HID];
  __shared__ float pctx[4][HID];
  __shared__ float ctx[HID];
  __shared__ float red[4];
  int b = blockIdx.x, tid = threadIdx.x;
  int lane = tid & 63, wave = tid >> 6;
  const float* cb = combined + (size_t)b * TLEN * HID;
  if (tid < HID) aw[tid] = att_w[tid];
  __syncthreads();
  float a0 = aw[lane], a1 = aw[lane + 64], a2 = aw[lane + 128];

  // scores: lanes = h (coalesced), butterfly-reduce across 64 lanes
  for (int t = wave * 128; t < wave * 128 + 128; ++t) {
    const float* r = cb + (size_t)t * HID;
    float p = a0 * r[lane] + a1 * r[lane + 64] + a2 * r[lane + 128];
#pragma unroll
    for (int o = 32; o; o >>= 1) p += __shfl_xor(p, o, 64);
    if (lane == 0) sc[t] = p;
  }
  __syncthreads();

  // softmax over T
  float lmax = -1e30f;
  for (int t = tid; t < TLEN; t += 256) lmax = fmaxf(lmax, sc[t]);
#pragma unroll
  for (int o = 32; o; o >>= 1) lmax = fmaxf(lmax, __shfl_xor(lmax, o, 64));
  if (lane == 0) red[wave] = lmax;
  __syncthreads();
  float m = fmaxf(fmaxf(red[0], red[1]), fmaxf(red[2], red[3]));
  __syncthreads();
  float lsum = 0.f;
  for (int t = tid; t < TLEN; t += 256) {
    float e = expf(sc[t] - m);
    sc[t] = e;
    lsum += e;
  }
#pragma unroll
  for (int o = 32; o; o >>= 1) lsum += __shfl_xor(lsum, o, 64);
  if (lane == 0) red[wave] = lsum;
  __syncthreads();
  float S = red[0] + red[1] + red[2] + red[3];
  float inv = 1.f / S;
  for (int t = tid; t < TLEN; t += 256) {
    float w = sc[t] * inv;
    sc[t] = w;
    dout[BATCH * NC + b * TLEN + t] = w;  // weights output (B,T,1)
  }
  __syncthreads();

  // context: coalesced (lanes = h), 4 t-groups reduced via LDS
#pragma unroll
  for (int p = 0; p < 3; ++p) {
    int h = p * 64 + lane;
    float c0 = 0.f, c1 = 0.f, c2 = 0.f, c3 = 0.f;
    for (int t = wave * 128; t < wave * 128 + 128; t += 4) {
      c0 += sc[t] * cb[(size_t)t * HID + h];
      c1 += sc[t + 1] * cb[(size_t)(t + 1) * HID + h];
      c2 += sc[t + 2] * cb[(size_t)(t + 2) * HID + h];
      c3 += sc[t + 3] * cb[(size_t)(t + 3) * HID + h];
    }
    pctx[wave][h] = (c0 + c1) + (c2 + c3);
  }
  __syncthreads();
  if (tid < HID)
    ctx[tid] = (pctx[0][tid] + pctx[1][tid]) + (pctx[2][tid] + pctx[3][tid]);
  __syncthreads();

  // FC
  if (tid < NC) {
    const float* wr = fc_w + (size_t)tid * HID;
    float s0 = fc_b[tid], s1 = 0.f, s2 = 0.f, s3 = 0.f;
#pragma unroll
    for (int h = 0; h < HID; h += 4) {
      s0 += ctx[h] * wr[h];
      s1 += ctx[h + 1] * wr[h + 1];
      s2 += ctx[h + 2] * wr[h + 2];
      s3 += ctx[h + 3] * wr[h + 3];
    }
    dout[b * NC + tid] = (s0 + s1) + (s2 + s3);  // logits (B,250)
  }
}

// ---------------- launcher ----------------

extern "C" void kernel_launch(void* const* d_in, const int* in_sizes, int n_in,
                              void* d_out, int out_size, void* d_ws, size_t ws_size,
                              hipStream_t stream) {
  const float* x = (const float*)d_in[0];
  const float* wih_rh = (const float*)d_in[1];
  const float* whh_rh = (const float*)d_in[2];
  const float* bih_rh = (const float*)d_in[3];
  const float* bhh_rh = (const float*)d_in[4];
  const float* wih_ra = (const float*)d_in[5];
  const float* whh_ra = (const float*)d_in[6];
  const float* bih_ra = (const float*)d_in[7];
  const float* bhh_ra = (const float*)d_in[8];
  const float* wih_lh = (const float*)d_in[9];
  const float* whh_lh = (const float*)d_in[10];
  const float* bih_lh = (const float*)d_in[11];
  const float* bhh_lh = (const float*)d_in[12];
  const float* wih_la = (const float*)d_in[13];
  const float* whh_la = (const float*)d_in[14];
  const float* bih_la = (const float*)d_in[15];
  const float* bhh_la = (const float*)d_in[16];
  const float* att_w = (const float*)d_in[17];
  const float* fc_w = (const float*)d_in[18];
  const float* fc_b = (const float*)d_in[19];

  // ws layout (~65.2 MB)
  char* p = (char*)d_ws;
  float* combined = (float*)p;                      p += (size_t)BATCH * TLEN * HID * 4;  // 50,331,648
  unsigned short* fHR = (unsigned short*)p;         p += (size_t)8 * TLEN * 16 * 48 * 2;  // 6,291,456
  unsigned short* fHL = (unsigned short*)p;         p += (size_t)8 * TLEN * 16 * 48 * 2;
  unsigned short* fAR = (unsigned short*)p;         p += (size_t)4 * TLEN * 32 * 8 * 2;   // 1,048,576
  unsigned short* fAL = (unsigned short*)p;         p += (size_t)4 * TLEN * 32 * 8 * 2;
  unsigned short* bt_rh = (unsigned short*)p;       p += 256 * 128 * 2;
  unsigned short* bt_lh = (unsigned short*)p;       p += 256 * 128 * 2;
  unsigned short* bt_ra = (unsigned short*)p;       p += 128 * 64 * 2;
  unsigned short* bt_la = (unsigned short*)p;

  prep_kernel<<<dim3((BATCH * TLEN + 255) / 256), 256, 0, stream>>>(x, fHR, fHL, fAR, fAL);
  pack_kernel<<<dim3(4), 256, 0, stream>>>(
      wih_rh, whh_rh, wih_ra, whh_ra, wih_lh, whh_lh, wih_la, whh_la,
      bt_rh, bt_ra, bt_lh, bt_la);
  lstm_kernel<<<dim3(24), 256, 0, stream>>>(
      fHR, fHL, fAR, fAL, bt_rh, bt_ra, bt_lh, bt_la,
      bih_rh, bhh_rh, bih_ra, bhh_ra, bih_lh, bhh_lh, bih_la, bhh_la,
      combined);
  attn_kernel<<<dim3(BATCH), 256, 0, stream>>>(combined, att_w, fc_w, fc_b, (float*)d_out);
}